// Round 7
// baseline (234.508 us; speedup 1.0000x reference)
//
#include <hip/hip_runtime.h>

// FRFT with diagonal transform matrices (Evec = I in the reference):
//   out[n,c,h,w] = Re( D[(h+128)%256] * D[(w+128)%256] ) * x[n,c,h,w]
// where D[i] = 16 * exp(-i * (pi/2) * a * l_i),  l_i = i (i<255), l_255 = 256.
//
// HARNESS FACTS (rocprof rounds 0-6):
//  - Live output is REAL-only, 134 MB f32; interleaved path is a dead fallback.
//  - dur_us ≈ 2 x 80 µs poison fills (fixed) + kernel.
//  - Kernel history: r0 66 | r2/r3 (NT) 72 | r4 (KIT=4, load-late) 70 |
//    r5 (table kernel) 71 | r6 (KIT=1, load-EARLY, f32x4, 32768 blk) 62.6 µs.
//  - Live levers: load issued BEFORE the sincos prologue; max block count;
//    16 B/lane both ways; plain (non-NT) stores.
//
// Round-7: the one clean untested cell — KIT=2 grid-stride with BOTH loads
// issued back-to-back before the sincos prologue (32 B/lane in flight under
// the f64 work), branch-free hot path (nvec4 = 16384*512 exactly), still
// 16384 blocks. Halves per-block fixed cost {launch, sincos, barrier}
// per byte moved relative to r6. Everything else identical to r6.

typedef float f32x2 __attribute__((ext_vector_type(2)));
typedef float f32x4 __attribute__((ext_vector_type(4)));

constexpr int HW    = 256;  // H == W == 256
constexpr int BLOCK = 256;
constexpr int KIT   = 2;    // f32x4 vectors per thread, grid-strided

__global__ __launch_bounds__(BLOCK) void frft_diag_kernel(
    const float* __restrict__ x,
    const float* __restrict__ order,
    float* __restrict__ out,
    int interleaved,
    int nvec4)   // number of f32x4 input vectors = total/4
{
    __shared__ alignas(16) f32x2 tbl[HW];

    const int t = threadIdx.x;
    const int stride = gridDim.x * BLOCK;              // f32x4 vectors per pass
    const int p0 = blockIdx.x * BLOCK + t;
    const int p1 = p0 + stride;

    // Issue both streaming loads FIRST (back-to-back dwordx4, 32 B/lane in
    // flight): their latency hides under the f64 sincos prologue.
    f32x4 xv0 = {0, 0, 0, 0}, xv1 = {0, 0, 0, 0};
    const bool l0 = (p0 < nvec4), l1 = (p1 < nvec4);
    if (l0) xv0 = ((const f32x4*)x)[p0];
    if (l1) xv1 = ((const f32x4*)x)[p1];

    // Build the shifted diagonal table once per block. Double precision:
    // phase reaches ~2400 rad; double sincos keeps argument-reduction
    // error negligible vs the 2% threshold. Proven fully hidden (r0/r6).
    {
        const int idx = t ^ 128;                       // (t + 128) % 256
        const double l = (idx == 255) ? 256.0 : (double)idx;
        const double theta = 1.5707963267948966 * (double)order[0] * l;
        double s, c;
        sincos(theta, &s, &c);
        tbl[t] = (f32x2){(float)(16.0 * c), (float)(16.0 * s)};
    }
    __syncthreads();

    // Element index e = 4p, so w = e & 255 = 4*(t & 63): lane-invariant.
    const int wbase = (t & 63) << 2;
    const f32x4 twA = *reinterpret_cast<const f32x4*>(&tbl[wbase]);      // c0,s0,c1,s1
    const f32x4 twB = *reinterpret_cast<const f32x4*>(&tbl[wbase + 2]);  // c2,s2,c3,s3

    const f32x2 th0 = tbl[(p0 >> 6) & (HW - 1)];       // wave-uniform ds_read_b64
    const f32x2 th1 = tbl[(p1 >> 6) & (HW - 1)];       // wave-uniform ds_read_b64

    // Re[(ch - i*sh)(cw - i*sw)] = ch*cw - sh*sw
    const float a0 = th0.x * twA.x - th0.y * twA.y;
    const float a1 = th0.x * twA.z - th0.y * twA.w;
    const float a2 = th0.x * twB.x - th0.y * twB.y;
    const float a3 = th0.x * twB.z - th0.y * twB.w;
    const float b0 = th1.x * twA.x - th1.y * twA.y;
    const float b1 = th1.x * twA.z - th1.y * twA.w;
    const float b2 = th1.x * twB.x - th1.y * twB.y;
    const float b3 = th1.x * twB.z - th1.y * twB.w;

    if (!interleaved) {
        // Hot path: real-only output, back-to-back dwordx4 stores.
        if (l0) {
            f32x4 o0 = { xv0.x * a0, xv0.y * a1, xv0.z * a2, xv0.w * a3 };
            ((f32x4*)out)[p0] = o0;
        }
        if (l1) {
            f32x4 o1 = { xv1.x * b0, xv1.y * b1, xv1.z * b2, xv1.w * b3 };
            ((f32x4*)out)[p1] = o1;
        }
    } else {
        // Dead in this harness (output is real-only); kept for safety.
        const float ai0 = th0.x * twA.y + th0.y * twA.x;
        const float ai1 = th0.x * twA.w + th0.y * twA.z;
        const float ai2 = th0.x * twB.y + th0.y * twB.x;
        const float ai3 = th0.x * twB.w + th0.y * twB.z;
        const float bi0 = th1.x * twA.y + th1.y * twA.x;
        const float bi1 = th1.x * twA.w + th1.y * twA.z;
        const float bi2 = th1.x * twB.y + th1.y * twB.x;
        const float bi3 = th1.x * twB.w + th1.y * twB.z;
        if (l0) {
            f32x4 oA = { xv0.x * a0, -xv0.x * ai0, xv0.y * a1, -xv0.y * ai1 };
            f32x4 oB = { xv0.z * a2, -xv0.z * ai2, xv0.w * a3, -xv0.w * ai3 };
            ((f32x4*)out)[2 * p0]     = oA;
            ((f32x4*)out)[2 * p0 + 1] = oB;
        }
        if (l1) {
            f32x4 oA = { xv1.x * b0, -xv1.x * bi0, xv1.y * b1, -xv1.y * bi1 };
            f32x4 oB = { xv1.z * b2, -xv1.z * bi2, xv1.w * b3, -xv1.w * bi3 };
            ((f32x4*)out)[2 * p1]     = oA;
            ((f32x4*)out)[2 * p1 + 1] = oB;
        }
    }
}

extern "C" void kernel_launch(void* const* d_in, const int* in_sizes, int n_in,
                              void* d_out, int out_size, void* d_ws, size_t ws_size,
                              hipStream_t stream) {
    const float* x     = (const float*)d_in[0];
    const float* order = (const float*)d_in[1];
    float* out = (float*)d_out;

    const int total = in_sizes[0];          // element count
    const int nvec4 = total / 4;            // f32x4 vectors
    const int interleaved = (out_size >= 2 * total) ? 1 : 0;

    const int per_block = BLOCK * KIT;      // 512 f32x4 per block (grid-stride)
    const int grid = (nvec4 + per_block - 1) / per_block;   // 16384 blocks
    frft_diag_kernel<<<grid, BLOCK, 0, stream>>>(x, order, out, interleaved, nvec4);
}

// Round 8
// 219.667 us; speedup vs baseline: 1.0676x; 1.0676x over previous
//
#include <hip/hip_runtime.h>

// FRFT with diagonal transform matrices (Evec = I in the reference):
//   out[n,c,h,w] = Re( D[(h+128)%256] * D[(w+128)%256] ) * x[n,c,h,w]
// where D[i] = 16 * exp(-i * (pi/2) * a * l_i),  l_i = i (i<255), l_255 = 256.
//
// HARNESS FACTS (rocprof rounds 0-7):
//  - Live output is REAL-only, 134 MB f32; interleaved path is a dead fallback.
//  - dur_us ≈ 2 x 80 µs poison fills (fixed, 6.7 TB/s) + kernel.
//  - Kernel history (inferred): r0 66 | r2/r3 (NT) 72 | r4 (KIT=4 load-late) 70
//    | r5 (table kernel) 71 | r6 (THIS SHAPE) 62.6 | r7 (KIT=2 stride) 72 µs.
//  - Block-count lever is monotone-confirmed: 32768 blocks optimal.
//    KIT>1 regresses regardless of load placement. NT stores regress.
//  - Kernel solo BW 3.2 TB/s is bounded by overlap with the fills' dirty-line
//    drain (device-aggregate 5.5 TB/s ≈ 82% of demonstrated 6.7 TB/s), not by
//    kernel-visible counters (VALUBusy 8%, occ 75%, 0 bank conflicts).
//
// This file: REVERT to the round-6 measured optimum, verbatim.
//  - KIT=1, grid = nvec4/256 = 32768 blocks (max resident parallelism).
//  - f32x4 load AND store (16 B/lane dense).
//  - Global load issued BEFORE the sincos prologue: ~900-cycle HBM latency
//    hides under the f64 table build instead of stalling after the barrier.
//  - Table built in-block (no extra launch); double sincos for accuracy
//    (phase reaches ~2400 rad).
//  - Lane-invariant w-factors hoisted from LDS once; wave-uniform tbl[h]
//    broadcast (ds_read_b64, conflict-free).

typedef float f32x2 __attribute__((ext_vector_type(2)));
typedef float f32x4 __attribute__((ext_vector_type(4)));

constexpr int HW    = 256;  // H == W == 256
constexpr int BLOCK = 256;

__global__ __launch_bounds__(BLOCK) void frft_diag_kernel(
    const float* __restrict__ x,
    const float* __restrict__ order,
    float* __restrict__ out,
    int interleaved,
    int nvec4)   // number of f32x4 input vectors = total/4
{
    __shared__ alignas(16) f32x2 tbl[HW];

    const int t = threadIdx.x;
    const int p = blockIdx.x * BLOCK + t;              // f32x4 index
    const bool live = (p < nvec4);

    // Issue the streaming load FIRST: independent of the table, so its
    // latency hides under the f64 sincos prologue below.
    f32x4 xv = {0, 0, 0, 0};
    if (live) xv = ((const f32x4*)x)[p];               // global_load_dwordx4

    // Build the shifted diagonal table once per block. Double precision:
    // phase reaches ~2400 rad; double sincos keeps argument-reduction
    // error negligible vs the 2% threshold. (r0/r6 proved this prologue is
    // fully hidden under the memory stream.)
    {
        const int idx = t ^ 128;                       // (t + 128) % 256
        const double l = (idx == 255) ? 256.0 : (double)idx;
        const double theta = 1.5707963267948966 * (double)order[0] * l;
        double s, c;
        sincos(theta, &s, &c);
        tbl[t] = (f32x2){(float)(16.0 * c), (float)(16.0 * s)};
    }
    __syncthreads();

    if (!live) return;

    // Element index e = 4p, so w = e & 255 = 4*(t & 63): lane-invariant.
    const int wbase = (t & 63) << 2;
    const f32x4 twA = *reinterpret_cast<const f32x4*>(&tbl[wbase]);      // c0,s0,c1,s1
    const f32x4 twB = *reinterpret_cast<const f32x4*>(&tbl[wbase + 2]);  // c2,s2,c3,s3
    const f32x2 th  = tbl[(p >> 6) & (HW - 1)];        // wave-uniform ds_read_b64

    // Re[(ch - i*sh)(cw - i*sw)] = ch*cw - sh*sw
    const float pr0 = th.x * twA.x - th.y * twA.y;
    const float pr1 = th.x * twA.z - th.y * twA.w;
    const float pr2 = th.x * twB.x - th.y * twB.y;
    const float pr3 = th.x * twB.z - th.y * twB.w;

    if (interleaved) {
        // Dead in this harness (output is real-only); kept for safety.
        const float pi0 = th.x * twA.y + th.y * twA.x;
        const float pi1 = th.x * twA.w + th.y * twA.z;
        const float pi2 = th.x * twB.y + th.y * twB.x;
        const float pi3 = th.x * twB.w + th.y * twB.z;
        f32x4 oA = { xv.x * pr0, -xv.x * pi0, xv.y * pr1, -xv.y * pi1 };
        f32x4 oB = { xv.z * pr2, -xv.z * pi2, xv.w * pr3, -xv.w * pi3 };
        ((f32x4*)out)[2 * p]     = oA;
        ((f32x4*)out)[2 * p + 1] = oB;
    } else {
        f32x4 o = { xv.x * pr0, xv.y * pr1, xv.z * pr2, xv.w * pr3 };
        ((f32x4*)out)[p] = o;                          // plain global_store_dwordx4
    }
}

extern "C" void kernel_launch(void* const* d_in, const int* in_sizes, int n_in,
                              void* d_out, int out_size, void* d_ws, size_t ws_size,
                              hipStream_t stream) {
    const float* x     = (const float*)d_in[0];
    const float* order = (const float*)d_in[1];
    float* out = (float*)d_out;

    const int total = in_sizes[0];          // element count
    const int nvec4 = total / 4;            // f32x4 vectors
    const int interleaved = (out_size >= 2 * total) ? 1 : 0;

    const int grid = (nvec4 + BLOCK - 1) / BLOCK;      // 32768 blocks
    frft_diag_kernel<<<grid, BLOCK, 0, stream>>>(x, order, out, interleaved, nvec4);
}